// Round 2
// baseline (457.465 us; speedup 1.0000x reference)
//
#include <hip/hip_runtime.h>
#include <hip/hip_bf16.h>

#define N_NODES 16384
#define KDIM    16384
#define HID     64
#define N_EDGES 524288
#define KSPLIT  4
#define KC      (KDIM / KSPLIT)   /* 4096 */
#define BK      64

typedef __bf16 bf16x8 __attribute__((ext_vector_type(8)));
typedef float  f32x4  __attribute__((ext_vector_type(4)));

__device__ __forceinline__ unsigned cvt_pk(float a, float b) {
    unsigned r;
    asm("v_cvt_pk_bf16_f32 %0, %1, %2" : "=v"(r) : "v"(a), "v"(b));
    return r;
}

// ---- W1 [K][64] f32  ->  W1t packed [64][K/2] u32 (2 bf16 per u32, pair = (2k, 2k+1))
__global__ void pack_w1t(const float* __restrict__ W1, unsigned* __restrict__ W1t) {
    int tid = blockIdx.x * 256 + threadIdx.x;       // 64*8192 threads
    int c  = tid & 63;
    int kp = tid >> 6;
    float f0 = W1[(size_t)(2 * kp)     * HID + c];
    float f1 = W1[(size_t)(2 * kp + 1) * HID + c];
    W1t[(size_t)c * (KDIM / 2) + kp] = cvt_pk(f0, f1);
}

__global__ void deg_init(float* deg) {
    int i = blockIdx.x * 256 + threadIdx.x;
    deg[i] = 1.0f;                                   // self-loop weight
}

__global__ void deg_acc(const int* __restrict__ ei, const float* __restrict__ w,
                        float* deg) {
    int e = blockIdx.x * 256 + threadIdx.x;
    atomicAdd(&deg[ei[N_EDGES + e]], w[e]);
}

__global__ void dinv_k(const float* __restrict__ deg, float* __restrict__ dinv) {
    int i = blockIdx.x * 256 + threadIdx.x;
    dinv[i] = rsqrtf(deg[i]);                        // deg >= 1 always
}

// ---- hpre = x @ W1  (bf16 MFMA, f32 accum, K-split with atomic accumulation)
__global__ __launch_bounds__(256) void gemm1(const float* __restrict__ x,
                                             const unsigned* __restrict__ w1t,
                                             float* __restrict__ hpre) {
    // swizzled LDS tiles: row stride 128B = 8 slots of 16B; slot ^= (row&7)
    __shared__ unsigned As_u[64 * 32];
    __shared__ unsigned Bs_u[64 * 32];

    const int t    = threadIdx.x;
    const int wave = t >> 6;
    const int lane = t & 63;
    const int row0 = blockIdx.x * 64;
    const int k00  = blockIdx.y * KC;

    const int a_row  = t >> 4;        // 0..15 (i*16 added)
    const int a_fq   = t & 15;        // float4 index in row
    const int a_slot = a_fq >> 1, a_half = a_fq & 1;
    const int fr_lo  = lane & 15, fr_hi = lane >> 4;

    f32x4 acc[4] = {{0.f,0.f,0.f,0.f},{0.f,0.f,0.f,0.f},{0.f,0.f,0.f,0.f},{0.f,0.f,0.f,0.f}};

    for (int k0 = k00; k0 < k00 + KC; k0 += BK) {
        __syncthreads();
        // stage A: 64 rows x 64 f32 -> bf16, swizzled
        #pragma unroll
        for (int i = 0; i < 4; ++i) {
            int row = a_row + i * 16;
            const float4 v = *(const float4*)(x + (size_t)(row0 + row) * KDIM + k0 + a_fq * 4);
            unsigned u0 = cvt_pk(v.x, v.y), u1 = cvt_pk(v.z, v.w);
            unsigned* dst = &As_u[row * 32 + ((a_slot ^ (row & 7)) << 2) + a_half * 2];
            dst[0] = u0; dst[1] = u1;
        }
        // stage B: w1t rows (output cols) 64 x 64 bf16, swizzled
        #pragma unroll
        for (int i = 0; i < 2; ++i) {
            int sid = t + 256 * i;
            int c = sid >> 3, slot = sid & 7;
            const uint4 v = *(const uint4*)(w1t + (size_t)c * (KDIM / 2) + (k0 >> 1) + slot * 4);
            *(uint4*)&Bs_u[c * 32 + ((slot ^ (c & 7)) << 2)] = v;
        }
        __syncthreads();
        // compute: wave owns rows wave*16..+15, all 64 cols
        #pragma unroll
        for (int kk = 0; kk < 2; ++kk) {
            int slot = kk * 4 + fr_hi;
            int ar = wave * 16 + fr_lo;
            bf16x8 a = *(const bf16x8*)&As_u[ar * 32 + ((slot ^ (ar & 7)) << 2)];
            #pragma unroll
            for (int ct = 0; ct < 4; ++ct) {
                int bc = ct * 16 + fr_lo;
                bf16x8 b = *(const bf16x8*)&Bs_u[bc * 32 + ((slot ^ (bc & 7)) << 2)];
                acc[ct] = __builtin_amdgcn_mfma_f32_16x16x32_bf16(a, b, acc[ct], 0, 0, 0);
            }
        }
    }
    // C layout (m89): col = lane&15, row = (lane>>4)*4 + reg
    #pragma unroll
    for (int ct = 0; ct < 4; ++ct) {
        int c = ct * 16 + fr_lo;
        #pragma unroll
        for (int r = 0; r < 4; ++r) {
            int row = wave * 16 + fr_hi * 4 + r;
            atomicAdd(&hpre[(size_t)(row0 + row) * HID + c], acc[ct][r]);
        }
    }
}

// ---- layer-1 aggregation: one wave per edge, lane = column
__global__ void agg1_k(const int* __restrict__ ei, const float* __restrict__ w,
                       const float* __restrict__ dinv, const float* __restrict__ hpre,
                       float* __restrict__ agg1) {
    int e    = (blockIdx.x * 256 + threadIdx.x) >> 6;
    int lane = threadIdx.x & 63;
    int s = ei[e];
    int d = ei[N_EDGES + e];
    float wn = dinv[s] * w[e] * dinv[d];
    atomicAdd(&agg1[(size_t)d * HID + lane], wn * hpre[(size_t)s * HID + lane]);
}

// ---- finalize layer 1 (+ self loop + bias + relu) fused with h @ W2 -> s
__global__ void fin1_k(const float* __restrict__ agg1, const float* __restrict__ hpre,
                       const float* __restrict__ dinv, const float* __restrict__ b1,
                       const float* __restrict__ W2, float* __restrict__ s_out) {
    int i = (blockIdx.x * 256 + threadIdx.x) >> 6;
    int c = threadIdx.x & 63;
    float self = dinv[i] * dinv[i];
    float v = agg1[(size_t)i * HID + c] + self * hpre[(size_t)i * HID + c] + b1[c];
    v = fmaxf(v, 0.0f);
    float tv = v * W2[c];
    #pragma unroll
    for (int off = 32; off > 0; off >>= 1) tv += __shfl_xor(tv, off);
    if (c == 0) s_out[i] = tv;
}

// ---- layer-2 aggregation: scalar per edge
__global__ void agg2_k(const int* __restrict__ ei, const float* __restrict__ w,
                       const float* __restrict__ dinv, const float* __restrict__ s,
                       float* __restrict__ out_acc) {
    int e = blockIdx.x * 256 + threadIdx.x;
    int sr = ei[e];
    int d  = ei[N_EDGES + e];
    atomicAdd(&out_acc[d], dinv[sr] * w[e] * dinv[d] * s[sr]);
}

__global__ void fin2_k(const float* __restrict__ out_acc, const float* __restrict__ dinv,
                       const float* __restrict__ s, const float* __restrict__ b2,
                       float* __restrict__ out) {
    int i = blockIdx.x * 256 + threadIdx.x;
    out[i] = out_acc[i] + dinv[i] * dinv[i] * s[i] + b2[0];
}

extern "C" void kernel_launch(void* const* d_in, const int* in_sizes, int n_in,
                              void* d_out, int out_size, void* d_ws, size_t ws_size,
                              hipStream_t stream) {
    const float* x  = (const float*)d_in[0];
    const int*   ei = (const int*)d_in[1];      // int32! (harness delivers integer inputs as int)
    const float* ew = (const float*)d_in[2];
    const float* W1 = (const float*)d_in[3];
    const float* b1 = (const float*)d_in[4];
    const float* W2 = (const float*)d_in[5];
    const float* b2 = (const float*)d_in[6];
    float* out = (float*)d_out;

    char* ws = (char*)d_ws;
    unsigned* w1t    = (unsigned*)(ws);                        // 2 MiB
    float*    hpre   = (float*)(ws + (2u << 20));              // 4 MiB
    float*    agg1   = (float*)(ws + (6u << 20));              // 4 MiB
    float*    outacc = (float*)(ws + (10u << 20));             // 64 KiB
    float*    deg    = (float*)(ws + (10u << 20) + (64u << 10));
    float*    dinv   = (float*)(ws + (10u << 20) + (128u << 10));
    float*    s      = (float*)(ws + (10u << 20) + (192u << 10));

    // zero hpre + agg1 + outacc (contiguous region)
    hipMemsetAsync(ws + (2u << 20), 0, (8u << 20) + (64u << 10), stream);

    pack_w1t<<<(64 * (KDIM / 2)) / 256, 256, 0, stream>>>(W1, w1t);
    deg_init<<<N_NODES / 256, 256, 0, stream>>>(deg);
    deg_acc<<<N_EDGES / 256, 256, 0, stream>>>(ei, ew, deg);
    dinv_k<<<N_NODES / 256, 256, 0, stream>>>(deg, dinv);
    gemm1<<<dim3(N_NODES / 64, KSPLIT), 256, 0, stream>>>(x, w1t, hpre);
    agg1_k<<<(N_EDGES * 64) / 256, 256, 0, stream>>>(ei, ew, dinv, hpre, agg1);
    fin1_k<<<N_NODES / 4, 256, 0, stream>>>(agg1, hpre, dinv, b1, W2, s);
    agg2_k<<<N_EDGES / 256, 256, 0, stream>>>(ei, ew, dinv, s, outacc);
    fin2_k<<<N_NODES / 256, 256, 0, stream>>>(outacc, dinv, s, b2, out);
}

// Round 3
// 397.847 us; speedup vs baseline: 1.1499x; 1.1499x over previous
//
#include <hip/hip_runtime.h>
#include <hip/hip_bf16.h>

#define N_NODES 16384
#define KDIM    16384
#define HID     64
#define N_EDGES 524288
#define KSPLIT  4
#define KC      (KDIM / KSPLIT)   /* 4096 */
#define BK      64
#define NT      (KC / BK)         /* 64 K-steps per block */

typedef __bf16 bf16x8 __attribute__((ext_vector_type(8)));
typedef float  f32x4  __attribute__((ext_vector_type(4)));

__device__ __forceinline__ unsigned cvt_pk(float a, float b) {
    unsigned r;
    asm("v_cvt_pk_bf16_f32 %0, %1, %2" : "=v"(r) : "v"(a), "v"(b));
    return r;
}

// ---- W1 [K][64] f32  ->  W1t packed [64][K/2] u32 (2 bf16 per u32, pair = (2k, 2k+1))
__global__ void pack_w1t(const float* __restrict__ W1, unsigned* __restrict__ W1t) {
    int tid = blockIdx.x * 256 + threadIdx.x;
    int c  = tid & 63;
    int kp = tid >> 6;
    float f0 = W1[(size_t)(2 * kp)     * HID + c];
    float f1 = W1[(size_t)(2 * kp + 1) * HID + c];
    W1t[(size_t)c * (KDIM / 2) + kp] = cvt_pk(f0, f1);
}

__global__ void deg_acc(const int* __restrict__ ei, const float* __restrict__ w,
                        float* deg) {
    int e = blockIdx.x * 256 + threadIdx.x;
    atomicAdd(&deg[ei[N_EDGES + e]], w[e]);
}

// deg was zeroed by memset; self-loop weight 1 folded in here
__global__ void dinv_k(const float* __restrict__ deg, float* __restrict__ dinv) {
    int i = blockIdx.x * 256 + threadIdx.x;
    dinv[i] = rsqrtf(deg[i] + 1.0f);
}

// ---- hpre = x @ W1  (bf16 MFMA, f32 accum, K-split, double-buffered pipeline)
__global__ __launch_bounds__(256, 4) void gemm1(const float* __restrict__ x,
                                                const unsigned* __restrict__ w1t,
                                                float* __restrict__ hpre) {
    // swizzled LDS tiles: row stride 128B = 8 slots of 16B; slot ^= (row&7)
    __shared__ unsigned As_u[2][64 * 32];
    __shared__ unsigned Bs_u[2][64 * 32];

    const int t    = threadIdx.x;
    const int wave = t >> 6;
    const int lane = t & 63;
    const int row0 = blockIdx.x * 64;
    const int k00  = blockIdx.y * KC;

    const int a_row  = t >> 4;        // 0..15 (i*16 added)
    const int a_fq   = t & 15;        // float4 index in row
    const int a_slot = a_fq >> 1, a_half = a_fq & 1;
    const int fr_lo  = lane & 15, fr_hi = lane >> 4;
    const int b_c    = t >> 3;        // B stage: col (i*32 added via sid)
    const int b_slot = t & 7;

    float4 pa[4];
    uint4  pb[2];

    f32x4 acc[4] = {{0.f,0.f,0.f,0.f},{0.f,0.f,0.f,0.f},{0.f,0.f,0.f,0.f},{0.f,0.f,0.f,0.f}};

    // ---- prologue: load + store tile 0
    #pragma unroll
    for (int i = 0; i < 4; ++i) {
        int row = a_row + i * 16;
        pa[i] = *(const float4*)(x + (size_t)(row0 + row) * KDIM + k00 + a_fq * 4);
    }
    #pragma unroll
    for (int i = 0; i < 2; ++i) {
        int c = b_c + i * 32;
        pb[i] = *(const uint4*)(w1t + (size_t)c * (KDIM / 2) + (k00 >> 1) + b_slot * 4);
    }
    #pragma unroll
    for (int i = 0; i < 4; ++i) {
        int row = a_row + i * 16;
        unsigned u0 = cvt_pk(pa[i].x, pa[i].y), u1 = cvt_pk(pa[i].z, pa[i].w);
        unsigned* dst = &As_u[0][row * 32 + ((a_slot ^ (row & 7)) << 2) + a_half * 2];
        dst[0] = u0; dst[1] = u1;
    }
    #pragma unroll
    for (int i = 0; i < 2; ++i) {
        int c = b_c + i * 32;
        *(uint4*)&Bs_u[0][c * 32 + ((b_slot ^ (c & 7)) << 2)] = pb[i];
    }
    __syncthreads();

    int cur = 0;
    for (int tt = 0; tt < NT; ++tt) {
        // issue next tile's global loads (latency hides under MFMA below)
        if (tt + 1 < NT) {
            int k0n = k00 + (tt + 1) * BK;
            #pragma unroll
            for (int i = 0; i < 4; ++i) {
                int row = a_row + i * 16;
                pa[i] = *(const float4*)(x + (size_t)(row0 + row) * KDIM + k0n + a_fq * 4);
            }
            #pragma unroll
            for (int i = 0; i < 2; ++i) {
                int c = b_c + i * 32;
                pb[i] = *(const uint4*)(w1t + (size_t)c * (KDIM / 2) + (k0n >> 1) + b_slot * 4);
            }
        }
        // compute current tile
        #pragma unroll
        for (int kk = 0; kk < 2; ++kk) {
            int slot = kk * 4 + fr_hi;
            int ar = wave * 16 + fr_lo;
            bf16x8 a = *(const bf16x8*)&As_u[cur][ar * 32 + ((slot ^ (ar & 7)) << 2)];
            #pragma unroll
            for (int ct = 0; ct < 4; ++ct) {
                int bc = ct * 16 + fr_lo;
                bf16x8 b = *(const bf16x8*)&Bs_u[cur][bc * 32 + ((slot ^ (bc & 7)) << 2)];
                acc[ct] = __builtin_amdgcn_mfma_f32_16x16x32_bf16(a, b, acc[ct], 0, 0, 0);
            }
        }
        // write next tile into the other buffer (safe: its readers finished
        // before the barrier that ended iteration tt-1)
        if (tt + 1 < NT) {
            #pragma unroll
            for (int i = 0; i < 4; ++i) {
                int row = a_row + i * 16;
                unsigned u0 = cvt_pk(pa[i].x, pa[i].y), u1 = cvt_pk(pa[i].z, pa[i].w);
                unsigned* dst = &As_u[cur ^ 1][row * 32 + ((a_slot ^ (row & 7)) << 2) + a_half * 2];
                dst[0] = u0; dst[1] = u1;
            }
            #pragma unroll
            for (int i = 0; i < 2; ++i) {
                int c = b_c + i * 32;
                *(uint4*)&Bs_u[cur ^ 1][c * 32 + ((b_slot ^ (c & 7)) << 2)] = pb[i];
            }
        }
        __syncthreads();
        cur ^= 1;
    }

    // C layout (m89): col = lane&15, row = (lane>>4)*4 + reg
    #pragma unroll
    for (int ct = 0; ct < 4; ++ct) {
        int c = ct * 16 + fr_lo;
        #pragma unroll
        for (int r = 0; r < 4; ++r) {
            int row = wave * 16 + fr_hi * 4 + r;
            atomicAdd(&hpre[(size_t)(row0 + row) * HID + c], acc[ct][r]);
        }
    }
}

// ---- layer-1 aggregation: one wave per edge, lane = column
__global__ void agg1_k(const int* __restrict__ ei, const float* __restrict__ w,
                       const float* __restrict__ dinv, const float* __restrict__ hpre,
                       float* __restrict__ agg1) {
    int e    = (blockIdx.x * 256 + threadIdx.x) >> 6;
    int lane = threadIdx.x & 63;
    int s = ei[e];
    int d = ei[N_EDGES + e];
    float wn = dinv[s] * w[e] * dinv[d];
    atomicAdd(&agg1[(size_t)d * HID + lane], wn * hpre[(size_t)s * HID + lane]);
}

// ---- finalize layer 1 (+ self loop + bias + relu) fused with h @ W2 -> s
__global__ void fin1_k(const float* __restrict__ agg1, const float* __restrict__ hpre,
                       const float* __restrict__ dinv, const float* __restrict__ b1,
                       const float* __restrict__ W2, float* __restrict__ s_out) {
    int i = (blockIdx.x * 256 + threadIdx.x) >> 6;
    int c = threadIdx.x & 63;
    float self = dinv[i] * dinv[i];
    float v = agg1[(size_t)i * HID + c] + self * hpre[(size_t)i * HID + c] + b1[c];
    v = fmaxf(v, 0.0f);
    float tv = v * W2[c];
    #pragma unroll
    for (int off = 32; off > 0; off >>= 1) tv += __shfl_xor(tv, off);
    if (c == 0) s_out[i] = tv;
}

// ---- layer-2 aggregation: scalar per edge
__global__ void agg2_k(const int* __restrict__ ei, const float* __restrict__ w,
                       const float* __restrict__ dinv, const float* __restrict__ s,
                       float* __restrict__ out_acc) {
    int e = blockIdx.x * 256 + threadIdx.x;
    int sr = ei[e];
    int d  = ei[N_EDGES + e];
    atomicAdd(&out_acc[d], dinv[sr] * w[e] * dinv[d] * s[sr]);
}

__global__ void fin2_k(const float* __restrict__ out_acc, const float* __restrict__ dinv,
                       const float* __restrict__ s, const float* __restrict__ b2,
                       float* __restrict__ out) {
    int i = blockIdx.x * 256 + threadIdx.x;
    out[i] = out_acc[i] + dinv[i] * dinv[i] * s[i] + b2[0];
}

extern "C" void kernel_launch(void* const* d_in, const int* in_sizes, int n_in,
                              void* d_out, int out_size, void* d_ws, size_t ws_size,
                              hipStream_t stream) {
    const float* x  = (const float*)d_in[0];
    const int*   ei = (const int*)d_in[1];      // int32 (harness delivers integers as int)
    const float* ew = (const float*)d_in[2];
    const float* W1 = (const float*)d_in[3];
    const float* b1 = (const float*)d_in[4];
    const float* W2 = (const float*)d_in[5];
    const float* b2 = (const float*)d_in[6];
    float* out = (float*)d_out;

    char* ws = (char*)d_ws;
    unsigned* w1t    = (unsigned*)(ws);                          // 2 MiB
    float*    hpre   = (float*)(ws + (2u << 20));                // 4 MiB
    float*    agg1   = (float*)(ws + (6u << 20));                // 4 MiB
    float*    outacc = (float*)(ws + (10u << 20));               // 64 KiB
    float*    deg    = (float*)(ws + (10u << 20) + (64u << 10)); // 64 KiB
    float*    dinv   = (float*)(ws + (10u << 20) + (128u << 10));
    float*    s      = (float*)(ws + (10u << 20) + (192u << 10));

    // zero hpre + agg1 + outacc + deg (contiguous region)
    hipMemsetAsync(ws + (2u << 20), 0, (8u << 20) + (128u << 10), stream);

    pack_w1t<<<(64 * (KDIM / 2)) / 256, 256, 0, stream>>>(W1, w1t);
    deg_acc<<<N_EDGES / 256, 256, 0, stream>>>(ei, ew, deg);
    dinv_k<<<N_NODES / 256, 256, 0, stream>>>(deg, dinv);
    gemm1<<<dim3(N_NODES / 64, KSPLIT), 256, 0, stream>>>(x, w1t, hpre);
    agg1_k<<<(N_EDGES * 64) / 256, 256, 0, stream>>>(ei, ew, dinv, hpre, agg1);
    fin1_k<<<N_NODES / 4, 256, 0, stream>>>(agg1, hpre, dinv, b1, W2, s);
    agg2_k<<<N_EDGES / 256, 256, 0, stream>>>(ei, ew, dinv, s, outacc);
    fin2_k<<<N_NODES / 256, 256, 0, stream>>>(outacc, dinv, s, b2, out);
}